// Round 4
// baseline (160.480 us; speedup 1.0000x reference)
//
#include <hip/hip_runtime.h>
#include <hip/hip_bf16.h>

// Problem constants: N=1024, C=32, T=8, V=64, K=3, CT=256
// out[n][c][v][t] = sum_k sum_j W[k][c*8+t][j] * U_k[j][v] + bias2T[c*8+t][v]
// U_k[j][v] = sum_u x[n][j][u] * A[k][u][v]
//
// R9: persistent 2-n blocks + k-rotation, attacking PHASE LOCK.
// Evidence: R5 (2 blk/CU) and R8 (4 blk/CU budget) have IDENTICAL dur
// (59us) and occupancy (18.5%) — residency ceilings aren't binding. All
// pipe floors are 4-15us vs dur 59us -> waves idle simultaneously: all
// 1024 blocks launch at t=0 with identical phase structure (x-burst, W-L2
// storm, barriers all chip-synchronized). Fix: grid 512, block does
// n1=bid then n2=bid+512 with a pipelined seam (xf2 loads issue during
// n1's last superstep where xf1 is dead; seam aw refill pulls n2's first
// W slice), plus k0=bid%3 rotation (acc2 accumulation commutes over k) to
// spread the W-L2 stream and let block phases drift.
// R6 lesson: never cap regs below liveness. R7 lesson: never thin the
// per-ks MFMA run. R8 lesson: residency ceiling != overlap.
// Raw lgkm-only barriers: all cross-wave comm is via LDS; global loads
// are wave-private -> legally stay outstanding across s_barrier.

typedef __attribute__((ext_vector_type(8))) short bf16x8;
typedef __attribute__((ext_vector_type(4))) float f32x4;

#define RAWBAR() asm volatile("s_waitcnt lgkmcnt(0)\n\ts_barrier" ::: "memory")

__device__ __forceinline__ short f2bf(float f) {
  union { float f; unsigned u; } c; c.f = f;
  unsigned r = c.u + 0x7FFFu + ((c.u >> 16) & 1u);   // RNE
  return (short)(r >> 16);
}

__device__ __forceinline__ unsigned pkbf(float a, float b) {
  float2 t; t.x = a; t.y = b;
  union { __hip_bfloat162 h; unsigned u; } c;
  c.h = __float22bfloat162_rn(t);   // v_cvt_pk_bf16_f32, RNE
  return c.u;
}

// ---------------- workspace layout (bytes) ----------------
// Wsw   : short[196608] @ 0        fragment-ordered W  (k,wv4,mt4,ks8,lane,e)
// Asw   : short[12288]  @ 393216   fragment-ordered A^T (k,ks,nt,lane,e)
// biasCM: float[16384]  @ 417792   column-major bias: biasCM[w*256 + d]
#define ASW_OFF  393216
#define BIAS_OFF 417792

__global__ __launch_bounds__(256) void prep_kernel(
    const float* __restrict__ W, const float* __restrict__ b,
    const float* __restrict__ A, short* __restrict__ Wsw,
    short* __restrict__ Asw, float* __restrict__ biasCM) {
  int t = blockIdx.x * 256 + threadIdx.x;
  if (t < 196608) {
    // Wsw flat = ((((k*4+wv)*4+mt)*8+ks)*64 + lane)*8 + e
    int e = t & 7, l = (t >> 3) & 63, ks = (t >> 9) & 7, mt = (t >> 12) & 3,
        wv = (t >> 14) & 3, k = t >> 16;
    int d = 64 * wv + 16 * mt + (l & 15);
    int c = 32 * ks + 8 * (l >> 4) + e;
    Wsw[t] = f2bf(W[(k * 256 + d) * 256 + c]);
  } else if (t < 196608 + 12288) {
    // Asw flat = (((k*2+ks)*4+nt)*64 + lane)*8 + e ; value = A[k][v][w]
    int t2 = t - 196608;
    int e = t2 & 7, l = (t2 >> 3) & 63, nt = (t2 >> 9) & 3, ks = (t2 >> 11) & 1,
        k = t2 >> 12;
    int w = nt * 16 + (l & 15);
    int v = ks * 32 + (l >> 4) * 8 + e;
    Asw[t2] = f2bf(A[(k * 64 + v) * 64 + w]);
  } else {
    // biasCM[w*256 + d] = sum_k (sum_v A[k][v][w]) * b[k][d]
    int t2 = t - 196608 - 12288;
    int w = t2 >> 8, d = t2 & 255;
    float s = 0.f;
    for (int k = 0; k < 3; ++k) {
      float cs = 0.f;
#pragma unroll
      for (int v = 0; v < 64; ++v) cs += A[(k * 64 + v) * 64 + w];
      s += cs * b[k * 256 + d];
    }
    biasCM[t2] = s;
  }
}

#define UT_STRIDE 264  // bf16 elems per Ut row (256 + 8 pad), 528B rows

// stage-1: compute U_k rows [64wv, 64wv+64), write transposed into Ut
__device__ __forceinline__ void stage1(
    const short* __restrict__ Asw, int k, const bf16x8 (&xf)[2][4],
    short* __restrict__ Utw, int wv, int lane, int li, int lq) {
  const short* AswK = Asw + k * 4096;
  f32x4 acc1[4][4];
#pragma unroll
  for (int mt = 0; mt < 4; ++mt)
#pragma unroll
    for (int nt = 0; nt < 4; ++nt)
      acc1[mt][nt] = (f32x4){0.f, 0.f, 0.f, 0.f};

#pragma unroll
  for (int ks = 0; ks < 2; ++ks) {
    bf16x8 bfr[4];
#pragma unroll
    for (int nt = 0; nt < 4; ++nt)
      bfr[nt] = *(const bf16x8*)(AswK + ((ks * 4 + nt) * 64 + lane) * 8);
#pragma unroll
    for (int mt = 0; mt < 4; ++mt)
#pragma unroll
      for (int nt = 0; nt < 4; ++nt)
        acc1[mt][nt] = __builtin_amdgcn_mfma_f32_16x16x32_bf16(
            xf[ks][mt], bfr[nt], acc1[mt][nt], 0, 0, 0);
  }

#pragma unroll
  for (int mt = 0; mt < 4; ++mt)
#pragma unroll
    for (int nt = 0; nt < 4; ++nt) {
      int w = nt * 16 + li;
      int ct = 64 * wv + 16 * mt + 4 * lq;
      union { unsigned u[2]; unsigned long long ull; } p;
      p.u[0] = pkbf(acc1[mt][nt][0], acc1[mt][nt][1]);
      p.u[1] = pkbf(acc1[mt][nt][2], acc1[mt][nt][3]);
      *(unsigned long long*)(&Utw[w * UT_STRIDE + ct]) = p.ull;
    }
}

// stage-2: acc2 += W-slice @ U (from Ut); refill rotate: ks<6 from WswK
// (ks+2), ks>=6 from WswR (ks-6) = next superstep's ks 0,1. WswR=null: skip.
__device__ __forceinline__ void stage2_8(
    const short* __restrict__ Ut, const short* __restrict__ WswK,
    const short* __restrict__ WswR, bf16x8 (&awA)[4], bf16x8 (&awB)[4],
    f32x4 (&acc2)[4][4], int li, int lq, int lane) {
#pragma unroll
  for (int ks = 0; ks < 8; ++ks) {
    bf16x8 bu[4];
#pragma unroll
    for (int nt = 0; nt < 4; ++nt)
      bu[nt] = *(const bf16x8*)(&Ut[(nt * 16 + li) * UT_STRIDE + 32 * ks + 8 * lq]);

    bf16x8 aw0[4];
#pragma unroll
    for (int mt = 0; mt < 4; ++mt) aw0[mt] = (ks & 1) ? awB[mt] : awA[mt];

    if (ks < 6) {
#pragma unroll
      for (int mt = 0; mt < 4; ++mt) {
        bf16x8 nv = *(const bf16x8*)(WswK + ((mt * 8 + ks + 2) * 64 + lane) * 8);
        if (ks & 1) awB[mt] = nv; else awA[mt] = nv;
      }
    } else if (WswR) {
#pragma unroll
      for (int mt = 0; mt < 4; ++mt) {
        bf16x8 nv = *(const bf16x8*)(WswR + ((mt * 8 + (ks - 6)) * 64 + lane) * 8);
        if (ks & 1) awB[mt] = nv; else awA[mt] = nv;
      }
    }

#pragma unroll
    for (int mt = 0; mt < 4; ++mt)
#pragma unroll
      for (int nt = 0; nt < 4; ++nt)
        acc2[mt][nt] = __builtin_amdgcn_mfma_f32_16x16x32_bf16(
            aw0[mt], bu[nt], acc2[mt][nt], 0, 0, 0);
  }
}

__device__ __forceinline__ void load_xf(const float* __restrict__ xn,
                                        bf16x8 (&xf)[2][4], int wv, int li,
                                        int lq) {
#pragma unroll
  for (int ks = 0; ks < 2; ++ks)
#pragma unroll
    for (int mt = 0; mt < 4; ++mt) {
      const float4* p =
          (const float4*)(xn + (64 * wv + 16 * mt + li) * 64 + 32 * ks + 8 * lq);
      float4 f0 = p[0], f1 = p[1];
      union { bf16x8 v; unsigned u[4]; } t;
      t.u[0] = pkbf(f0.x, f0.y); t.u[1] = pkbf(f0.z, f0.w);
      t.u[2] = pkbf(f1.x, f1.y); t.u[3] = pkbf(f1.z, f1.w);
      xf[ks][mt] = t.v;
    }
}

__device__ __forceinline__ void load_bias(const float* __restrict__ biasCM,
                                          f32x4 (&acc2)[4][4], int wv, int li,
                                          int lq) {
#pragma unroll
  for (int mt = 0; mt < 4; ++mt)
#pragma unroll
    for (int nt = 0; nt < 4; ++nt) {
      const float4 bb = *(const float4*)(biasCM + (nt * 16 + li) * 256 +
                                         64 * wv + 16 * mt + 4 * lq);
      acc2[mt][nt] = (f32x4){bb.x, bb.y, bb.z, bb.w};
    }
}

// d = 64wv+16mt+4lq+r -> c = 8wv+2mt+(lq>>1), t = 4(lq&1)+r, w = 16nt+li
__device__ __forceinline__ void store_out(float* __restrict__ outn,
                                          const f32x4 (&acc2)[4][4], int wv,
                                          int li, int lq) {
#pragma unroll
  for (int mt = 0; mt < 4; ++mt)
#pragma unroll
    for (int nt = 0; nt < 4; ++nt) {
      float4 vv;
      vv.x = acc2[mt][nt][0];
      vv.y = acc2[mt][nt][1];
      vv.z = acc2[mt][nt][2];
      vv.w = acc2[mt][nt][3];
      *(float4*)(outn + (8 * wv + 2 * mt + (lq >> 1)) * 512 +
                 (nt * 16 + li) * 8 + 4 * (lq & 1)) = vv;
    }
}

__global__ __launch_bounds__(256, 2) void gcn_main(
    const float* __restrict__ x, const short* __restrict__ Wsw,
    const short* __restrict__ Asw, const float* __restrict__ biasCM,
    float* __restrict__ out) {
  __shared__ short Ut[64 * UT_STRIDE];  // 33792 B

  const int tid = threadIdx.x;
  const int wv = tid >> 6;        // wave 0..3, owns d-rows [64wv, 64wv+64)
  const int lane = tid & 63;
  const int li = lane & 15;
  const int lq = lane >> 4;

  const int bid = blockIdx.x;     // n1 = bid, n2 = bid + 512
  const int k0 = bid % 3;         // rotated k order: k0, k1, k2
  const int k1 = (k0 + 1 < 3) ? k0 + 1 : 0;
  const int k2 = (k1 + 1 < 3) ? k1 + 1 : 0;

  const short* Wk0 = Wsw + (k0 * 4 + wv) * 16384;
  const short* Wk1 = Wsw + (k1 * 4 + wv) * 16384;
  const short* Wk2 = Wsw + (k2 * 4 + wv) * 16384;

  const float* xn1 = x + (size_t)bid * 16384;
  const float* xn2 = x + (size_t)(bid + 512) * 16384;
  float* out1 = out + (size_t)bid * 16384;
  float* out2 = out + (size_t)(bid + 512) * 16384;

  // ================= n1 prologue =================
  bf16x8 xf[2][4];
  load_xf(xn1, xf, wv, li, lq);       // longest-latency loads first
  f32x4 acc2[4][4];
  load_bias(biasCM, acc2, wv, li, lq);
  stage1(Asw, k0, xf, Ut, wv, lane, li, lq);

  bf16x8 awA[4], awB[4];
#pragma unroll
  for (int mt = 0; mt < 4; ++mt) {
    awA[mt] = *(const bf16x8*)(Wk0 + ((mt * 8 + 0) * 64 + lane) * 8);
    awB[mt] = *(const bf16x8*)(Wk0 + ((mt * 8 + 1) * 64 + lane) * 8);
  }
  RAWBAR();  // Ut(k0) visible; aw loads stay outstanding

  // ================= n1 supersteps (k0 -> k1 -> k2) =================
  stage2_8(Ut, Wk0, Wk1, awA, awB, acc2, li, lq, lane);
  RAWBAR();  stage1(Asw, k1, xf, Ut, wv, lane, li, lq);  RAWBAR();
  stage2_8(Ut, Wk1, Wk2, awA, awB, acc2, li, lq, lane);
  RAWBAR();  stage1(Asw, k2, xf, Ut, wv, lane, li, lq);  RAWBAR();

  // seam prefetch: xf dead after the stage1 above -> xf2 can reuse its regs
  bf16x8 xf2[2][4];
  load_xf(xn2, xf2, wv, li, lq);

  // last n1 superstep; refill rotate pulls n2's first W slice (k0, ks 0,1)
  stage2_8(Ut, Wk2, Wk0, awA, awB, acc2, li, lq, lane);
  store_out(out1, acc2, wv, li, lq);

  // ================= seam =================
  load_bias(biasCM, acc2, wv, li, lq);
  RAWBAR();  // WAR: all waves' n1 stage2(k2) Ut reads complete
  stage1(Asw, k0, xf2, Ut, wv, lane, li, lq);
  RAWBAR();  // Ut(n2,k0) visible; awA/awB already hold n2's k0 ks0,1

  // ================= n2 supersteps =================
  stage2_8(Ut, Wk0, Wk1, awA, awB, acc2, li, lq, lane);
  RAWBAR();  stage1(Asw, k1, xf2, Ut, wv, lane, li, lq);  RAWBAR();
  stage2_8(Ut, Wk1, Wk2, awA, awB, acc2, li, lq, lane);
  RAWBAR();  stage1(Asw, k2, xf2, Ut, wv, lane, li, lq);  RAWBAR();
  stage2_8(Ut, Wk2, nullptr, awA, awB, acc2, li, lq, lane);
  store_out(out2, acc2, wv, li, lq);
}

extern "C" void kernel_launch(void* const* d_in, const int* in_sizes, int n_in,
                              void* d_out, int out_size, void* d_ws, size_t ws_size,
                              hipStream_t stream) {
  (void)in_sizes; (void)n_in; (void)out_size; (void)ws_size;
  const float* x = (const float*)d_in[0];
  const float* W = (const float*)d_in[1];
  const float* b = (const float*)d_in[2];
  const float* A = (const float*)d_in[3];
  float* out = (float*)d_out;

  short* Wsw = (short*)d_ws;
  short* Asw = (short*)((char*)d_ws + ASW_OFF);
  float* biasCM = (float*)((char*)d_ws + BIAS_OFF);

  // prep: 196608 (W) + 12288 (A) + 16384 (bias) = 225280 threads = 880 blocks
  prep_kernel<<<880, 256, 0, stream>>>(W, b, A, Wsw, Asw, biasCM);
  // 512 persistent blocks: n1 = bid, n2 = bid + 512, k-rotated
  gcn_main<<<512, 256, 0, stream>>>(x, Wsw, Asw, biasCM, out);
}

// Round 5
// 148.551 us; speedup vs baseline: 1.0803x; 1.0803x over previous
//
#include <hip/hip_runtime.h>
#include <hip/hip_bf16.h>

// Problem constants: N=1024, C=32, T=8, V=64, K=3, CT=256
// out[n][c][v][t] = sum_k sum_j W[k][c*8+t][j] * U_k[j][v] + bias2T[c*8+t][v]
// U_k[j][v] = sum_u x[n][j][u] * A[k][u][v]
//
// R10 = R8 (59us baseline: single Ut, raw lgkm-only barriers, 1024 blocks,
// nt=4-thick stage2, depth-2 aw rotate w/ cross-k refill) + ONE change:
// stage2's bu LDS reads are double-buffered one ks-step ahead, so the
// ~120-156cy ds_read_b128 latency overlaps the previous step's 16 MFMAs
// instead of preceding them. Evidence this is the lever: MFMA cycle-sum,
// FETCH, conflicts all invariant R5-R9; residency ceiling irrelevant
// (R5==R8); thinner MFMA runs regress superlinearly (R7) -> per-ks-step
// dependent chain {ds_read -> lgkm -> MFMA} x24/block is the critical path
// at ~1.5 waves/SIMD effective overlap.
// Cost: +32 transient VGPR (~150 total, 3 waves/SIMD, no spill - R8 showed
// blocks/CU beyond 2 buys nothing). Stage1 untouched (smaller exposure;
// touching it risks the ~192-reg peak = spill cliff).
// Spill canary: WRITE_SIZE must stay exactly 65536 KB (R6/R9 lesson).
// R7 lesson: never thin the per-ks MFMA run. R8 lesson: residency ceiling
// != overlap. Raw-barrier safety: cross-wave comm is LDS-only; every wave
// drains lgkmcnt(0) before s_barrier; global loads are wave-private and
// legally stay outstanding across s_barrier (waited at use).

typedef __attribute__((ext_vector_type(8))) short bf16x8;
typedef __attribute__((ext_vector_type(4))) float f32x4;

#define RAWBAR() asm volatile("s_waitcnt lgkmcnt(0)\n\ts_barrier" ::: "memory")

__device__ __forceinline__ short f2bf(float f) {
  union { float f; unsigned u; } c; c.f = f;
  unsigned r = c.u + 0x7FFFu + ((c.u >> 16) & 1u);   // RNE
  return (short)(r >> 16);
}

__device__ __forceinline__ unsigned pkbf(float a, float b) {
  float2 t; t.x = a; t.y = b;
  union { __hip_bfloat162 h; unsigned u; } c;
  c.h = __float22bfloat162_rn(t);   // v_cvt_pk_bf16_f32, RNE
  return c.u;
}

// ---------------- workspace layout (bytes) ----------------
// Wsw   : short[196608] @ 0        fragment-ordered W  (k,wv4,mt4,ks8,lane,e)
// Asw   : short[12288]  @ 393216   fragment-ordered A^T (k,ks,nt,lane,e)
// biasCM: float[16384]  @ 417792   column-major bias: biasCM[w*256 + d]
#define ASW_OFF  393216
#define BIAS_OFF 417792

__global__ __launch_bounds__(256) void prep_kernel(
    const float* __restrict__ W, const float* __restrict__ b,
    const float* __restrict__ A, short* __restrict__ Wsw,
    short* __restrict__ Asw, float* __restrict__ biasCM) {
  int t = blockIdx.x * 256 + threadIdx.x;
  if (t < 196608) {
    // Wsw flat = ((((k*4+wv)*4+mt)*8+ks)*64 + lane)*8 + e
    int e = t & 7, l = (t >> 3) & 63, ks = (t >> 9) & 7, mt = (t >> 12) & 3,
        wv = (t >> 14) & 3, k = t >> 16;
    int d = 64 * wv + 16 * mt + (l & 15);
    int c = 32 * ks + 8 * (l >> 4) + e;
    Wsw[t] = f2bf(W[(k * 256 + d) * 256 + c]);
  } else if (t < 196608 + 12288) {
    // Asw flat = (((k*2+ks)*4+nt)*64 + lane)*8 + e ; value = A[k][v][w]
    int t2 = t - 196608;
    int e = t2 & 7, l = (t2 >> 3) & 63, nt = (t2 >> 9) & 3, ks = (t2 >> 11) & 1,
        k = t2 >> 12;
    int w = nt * 16 + (l & 15);
    int v = ks * 32 + (l >> 4) * 8 + e;
    Asw[t2] = f2bf(A[(k * 64 + v) * 64 + w]);
  } else {
    // biasCM[w*256 + d] = sum_k (sum_v A[k][v][w]) * b[k][d]
    int t2 = t - 196608 - 12288;
    int w = t2 >> 8, d = t2 & 255;
    float s = 0.f;
    for (int k = 0; k < 3; ++k) {
      float cs = 0.f;
#pragma unroll
      for (int v = 0; v < 64; ++v) cs += A[(k * 64 + v) * 64 + w];
      s += cs * b[k * 256 + d];
    }
    biasCM[t2] = s;
  }
}

#define UT_STRIDE 264  // bf16 elems per Ut row (256 + 8 pad), 528B rows

// stage-1: compute U_k rows [64wv, 64wv+64), write transposed into Ut
__device__ __forceinline__ void stage1(
    const short* __restrict__ Asw, int k, const bf16x8 (&xf)[2][4],
    short* __restrict__ Utw, int wv, int lane, int li, int lq) {
  const short* AswK = Asw + k * 4096;
  f32x4 acc1[4][4];
#pragma unroll
  for (int mt = 0; mt < 4; ++mt)
#pragma unroll
    for (int nt = 0; nt < 4; ++nt)
      acc1[mt][nt] = (f32x4){0.f, 0.f, 0.f, 0.f};

#pragma unroll
  for (int ks = 0; ks < 2; ++ks) {
    bf16x8 bfr[4];
#pragma unroll
    for (int nt = 0; nt < 4; ++nt)
      bfr[nt] = *(const bf16x8*)(AswK + ((ks * 4 + nt) * 64 + lane) * 8);
#pragma unroll
    for (int mt = 0; mt < 4; ++mt)
#pragma unroll
      for (int nt = 0; nt < 4; ++nt)
        acc1[mt][nt] = __builtin_amdgcn_mfma_f32_16x16x32_bf16(
            xf[ks][mt], bfr[nt], acc1[mt][nt], 0, 0, 0);
  }

#pragma unroll
  for (int mt = 0; mt < 4; ++mt)
#pragma unroll
    for (int nt = 0; nt < 4; ++nt) {
      int w = nt * 16 + li;
      int ct = 64 * wv + 16 * mt + 4 * lq;
      union { unsigned u[2]; unsigned long long ull; } p;
      p.u[0] = pkbf(acc1[mt][nt][0], acc1[mt][nt][1]);
      p.u[1] = pkbf(acc1[mt][nt][2], acc1[mt][nt][3]);
      *(unsigned long long*)(&Utw[w * UT_STRIDE + ct]) = p.ull;
    }
}

__global__ __launch_bounds__(256, 2) void gcn_main(
    const float* __restrict__ x, const short* __restrict__ Wsw,
    const short* __restrict__ Asw, const float* __restrict__ biasCM,
    float* __restrict__ out) {
  __shared__ short Ut[64 * UT_STRIDE];  // 33792 B

  const int tid = threadIdx.x;
  const int wv = tid >> 6;        // wave 0..3, owns d-rows [64wv, 64wv+64)
  const int lane = tid & 63;
  const int li = lane & 15;
  const int lq = lane >> 4;
  const int n = blockIdx.x;

  const float* xn = x + (size_t)n * 16384;
  float* outn = out + (size_t)n * 16384;

  // ---- acc2 init = bias (epilogue becomes a pure store); biasCM is L2-hot
  f32x4 acc2[4][4];
#pragma unroll
  for (int mt = 0; mt < 4; ++mt)
#pragma unroll
    for (int nt = 0; nt < 4; ++nt) {
      const float4 bb = *(const float4*)(biasCM + (nt * 16 + li) * 256 +
                                         64 * wv + 16 * mt + 4 * lq);
      acc2[mt][nt] = (f32x4){bb.x, bb.y, bb.z, bb.w};
    }

  // ---- stage-1 A-operand: wave's 64x64 block of Xn, registers, k-invariant
  bf16x8 xf[2][4];
#pragma unroll
  for (int ks = 0; ks < 2; ++ks)
#pragma unroll
    for (int mt = 0; mt < 4; ++mt) {
      const float4* p =
          (const float4*)(xn + (64 * wv + 16 * mt + li) * 64 + 32 * ks + 8 * lq);
      float4 f0 = p[0], f1 = p[1];
      union { bf16x8 v; unsigned u[4]; } t;
      t.u[0] = pkbf(f0.x, f0.y); t.u[1] = pkbf(f0.z, f0.w);
      t.u[2] = pkbf(f1.x, f1.y); t.u[3] = pkbf(f1.z, f1.w);
      xf[ks][mt] = t.v;
    }

  // ---- preamble: U_0 -> Ut; aw(k=0, ks=0,1) prefetch stays in flight
  stage1(Asw, 0, xf, Ut, wv, lane, li, lq);

  bf16x8 awA[4], awB[4];
  {
    const short* W0 = Wsw + (0 * 4 + wv) * 16384;
#pragma unroll
    for (int mt = 0; mt < 4; ++mt) {
      awA[mt] = *(const bf16x8*)(W0 + ((mt * 8 + 0) * 64 + lane) * 8);
      awB[mt] = *(const bf16x8*)(W0 + ((mt * 8 + 1) * 64 + lane) * 8);
    }
  }

  RAWBAR();  // Ut(k=0) visible; aw loads remain outstanding (no vmcnt drain)

#pragma unroll
  for (int k = 0; k < 3; ++k) {
    const short* WswK = Wsw + (k * 4 + wv) * 16384;
    const short* WswN = Wsw + ((k + 1) * 4 + wv) * 16384;  // next k (k<2 only)

    // ---------- stage 2: acc2 += W_k[rows 64wv..] @ U_k (from Ut) ----------
    // bu is double-buffered one ks-step ahead: step ks issues ks+1's
    // ds_read_b128 before its MFMAs, so ds latency hides under them.
    bf16x8 buA[4], buB[4];
#pragma unroll
    for (int nt = 0; nt < 4; ++nt)
      buA[nt] = *(const bf16x8*)(&Ut[(nt * 16 + li) * UT_STRIDE + 8 * lq]);

#pragma unroll
    for (int ks = 0; ks < 8; ++ks) {
      // issue next step's bu reads first (depth-1 LDS pipeline)
      if (ks < 7) {
#pragma unroll
        for (int nt = 0; nt < 4; ++nt) {
          bf16x8 nb = *(const bf16x8*)(&Ut[(nt * 16 + li) * UT_STRIDE +
                                           32 * (ks + 1) + 8 * lq]);
          if (ks & 1) buA[nt] = nb; else buB[nt] = nb;
        }
      }

      bf16x8 bu0[4], aw0[4];
#pragma unroll
      for (int nt = 0; nt < 4; ++nt) bu0[nt] = (ks & 1) ? buB[nt] : buA[nt];
#pragma unroll
      for (int mt = 0; mt < 4; ++mt) aw0[mt] = (ks & 1) ? awB[mt] : awA[mt];

      // depth-2 aw rotate; at ks=6,7 refill from NEXT k's slice. These
      // loads cross the raw barriers without being drained (waited at use).
      if (ks < 6) {
#pragma unroll
        for (int mt = 0; mt < 4; ++mt) {
          bf16x8 nv = *(const bf16x8*)(WswK + ((mt * 8 + ks + 2) * 64 + lane) * 8);
          if (ks & 1) awB[mt] = nv; else awA[mt] = nv;
        }
      } else if (k < 2) {
#pragma unroll
        for (int mt = 0; mt < 4; ++mt) {
          bf16x8 nv = *(const bf16x8*)(WswN + ((mt * 8 + (ks - 6)) * 64 + lane) * 8);
          if (ks & 1) awB[mt] = nv; else awA[mt] = nv;
        }
      }

#pragma unroll
      for (int mt = 0; mt < 4; ++mt)
#pragma unroll
        for (int nt = 0; nt < 4; ++nt)
          acc2[mt][nt] = __builtin_amdgcn_mfma_f32_16x16x32_bf16(
              aw0[mt], bu0[nt], acc2[mt][nt], 0, 0, 0);
    }

    // ---------- single-buffer handoff: WAR barrier, write U_{k+1}, RAW
    // barrier. Both are lgkm-only: every wave's LDS ops complete before it
    // enters the barrier, so reads(k) finish before writes(k+1) start.
    if (k < 2) {
      RAWBAR();                              // stage2(k) reads done (WAR)
      stage1(Asw, k + 1, xf, Ut, wv, lane, li, lq);
      RAWBAR();                              // Ut(k+1) visible (RAW)
    }
  }

  // ---------- epilogue: direct float4 stores from C-layout ----------
  // d = 64wv+16mt+4lq+r -> c = 8wv+2mt+(lq>>1), t = 4(lq&1)+r, w = 16nt+li
#pragma unroll
  for (int mt = 0; mt < 4; ++mt)
#pragma unroll
    for (int nt = 0; nt < 4; ++nt) {
      float4 vv;
      vv.x = acc2[mt][nt][0];
      vv.y = acc2[mt][nt][1];
      vv.z = acc2[mt][nt][2];
      vv.w = acc2[mt][nt][3];
      *(float4*)(outn + (8 * wv + 2 * mt + (lq >> 1)) * 512 +
                 (nt * 16 + li) * 8 + 4 * (lq & 1)) = vv;
    }
}

extern "C" void kernel_launch(void* const* d_in, const int* in_sizes, int n_in,
                              void* d_out, int out_size, void* d_ws, size_t ws_size,
                              hipStream_t stream) {
  (void)in_sizes; (void)n_in; (void)out_size; (void)ws_size;
  const float* x = (const float*)d_in[0];
  const float* W = (const float*)d_in[1];
  const float* b = (const float*)d_in[2];
  const float* A = (const float*)d_in[3];
  float* out = (float*)d_out;

  short* Wsw = (short*)d_ws;
  short* Asw = (short*)((char*)d_ws + ASW_OFF);
  float* biasCM = (float*)((char*)d_ws + BIAS_OFF);

  // prep: 196608 (W) + 12288 (A) + 16384 (bias) = 225280 threads = 880 blocks
  prep_kernel<<<880, 256, 0, stream>>>(W, b, A, Wsw, Asw, biasCM);
  gcn_main<<<1024, 256, 0, stream>>>(x, Wsw, Asw, biasCM, out);
}